// Round 1
// baseline (499.955 us; speedup 1.0000x reference)
//
#include <hip/hip_runtime.h>
#include <hip/hip_bf16.h>
#include <cstdint>
#include <cstddef>

#define C_CLS   100000
#define D_FEAT  512
#define B_ROWS  512

#define COSM 0.8775825618903728f
#define SINM 0.479425538604203f
#define TH_  (-0.8775825618903728f)
#define MM_  0.2397127693021015f   /* sin(0.5)*0.5 */

typedef __bf16 bf16x8 __attribute__((ext_vector_type(8)));
typedef __bf16 bf16x4 __attribute__((ext_vector_type(4)));
typedef float  f32x4  __attribute__((ext_vector_type(4)));

typedef __attribute__((address_space(3))) void lds_void;
typedef const __attribute__((address_space(1))) void g_void;

__device__ __forceinline__ void async_copy16(const void* g, void* l) {
    __builtin_amdgcn_global_load_lds((g_void*)g, (lds_void*)l, 16, 0, 0);
}

// ---------------- kernel 1: normalize x rows -> bf16, zero accumulators ----
__global__ void k_xnorm(const float* __restrict__ x, __bf16* __restrict__ xn,
                        float* __restrict__ row_sum, float* __restrict__ tlogit) {
    const int row  = blockIdx.x;          // 512 blocks
    const int lane = threadIdx.x;         // 64 threads
    const f32x4* p = (const f32x4*)(x + (size_t)row * D_FEAT);
    f32x4 a = p[lane];
    f32x4 b = p[lane + 64];
    float s = a[0]*a[0] + a[1]*a[1] + a[2]*a[2] + a[3]*a[3]
            + b[0]*b[0] + b[1]*b[1] + b[2]*b[2] + b[3]*b[3];
    #pragma unroll
    for (int m = 32; m >= 1; m >>= 1) s += __shfl_xor(s, m, 64);
    const float inv = 1.0f / fmaxf(sqrtf(s), 1e-12f);
    bf16x4 o0 = { (__bf16)(a[0]*inv), (__bf16)(a[1]*inv), (__bf16)(a[2]*inv), (__bf16)(a[3]*inv) };
    bf16x4 o1 = { (__bf16)(b[0]*inv), (__bf16)(b[1]*inv), (__bf16)(b[2]*inv), (__bf16)(b[3]*inv) };
    *(bf16x4*)(xn + (size_t)row * D_FEAT + lane * 4)       = o0;
    *(bf16x4*)(xn + (size_t)row * D_FEAT + 256 + lane * 4) = o1;
    if (lane == 0) { row_sum[row] = 0.0f; tlogit[row] = 0.0f; }
}

// ---------------- kernel 2: weight row inverse norms ----------------------
__global__ void k_wnorm(const float* __restrict__ w, float* __restrict__ inv_wn) {
    const int row  = blockIdx.x * 4 + (threadIdx.x >> 6);   // 25000 blocks x 4 rows
    const int lane = threadIdx.x & 63;
    if (row >= C_CLS) return;
    const f32x4* p = (const f32x4*)(w + (size_t)row * D_FEAT);
    f32x4 a = p[lane];
    f32x4 b = p[lane + 64];
    float s = a[0]*a[0] + a[1]*a[1] + a[2]*a[2] + a[3]*a[3]
            + b[0]*b[0] + b[1]*b[1] + b[2]*b[2] + b[3]*b[3];
    #pragma unroll
    for (int m = 32; m >= 1; m >>= 1) s += __shfl_xor(s, m, 64);
    if (lane == 0) inv_wn[row] = 1.0f / fmaxf(sqrtf(s), 1e-12f);
}

// ---------------- kernel 3: MFMA GEMM + fused ArcFace epilogue ------------
// grid: 4 block_m (batch) x 782 block_n (classes), block_m fastest for L2/L3 reuse.
__global__ __launch_bounds__(256, 2) void k_gemm(
        const __bf16* __restrict__ xn, const float* __restrict__ w,
        const float* __restrict__ inv_wn, const int* __restrict__ y,
        float* __restrict__ row_sum, float* __restrict__ tlogit) {

    __shared__ __align__(16) __bf16 As[4 * 128 * 8];   // [quad][row][8] bf16 : 8 KB
    __shared__ __align__(16) float  Bs[4 * 128 * 8];   // [quad][row][8] f32  : 16 KB
    __shared__ int ys[128];

    const int tid = threadIdx.x;
    const int bm  = blockIdx.x & 3;
    const int bn  = blockIdx.x >> 2;

    if (tid < 128) ys[tid] = y[bm * 128 + tid];

    const int wave = tid >> 6;
    const int lane = tid & 63;
    const int wm   = wave >> 1;     // 0..1
    const int wn   = wave & 1;      // 0..1
    const int quad = lane >> 4;     // 0..3
    const int l15  = lane & 15;

    f32x4 acc[4][4];
    #pragma unroll
    for (int i = 0; i < 4; ++i)
        #pragma unroll
        for (int j = 0; j < 4; ++j) acc[i][j] = (f32x4){0.f, 0.f, 0.f, 0.f};

    for (int kt = 0; kt < 16; ++kt) {
        const int k0 = kt * 32;
        // stage A: 512 x 16B chunks; chunk c -> quad=c>>7, row=c&127
        #pragma unroll
        for (int i = 0; i < 2; ++i) {
            const int c  = tid + i * 256;
            const int qc = c >> 7, rc = c & 127;
            const __bf16* g = xn + (size_t)(bm * 128 + rc) * D_FEAT + k0 + qc * 8;
            async_copy16(g, &As[(size_t)c * 8]);
        }
        // stage B (fp32): 1024 x 16B chunks; chunk c -> quad=c>>8, row=(c>>1)&127, half=c&1
        #pragma unroll
        for (int i = 0; i < 4; ++i) {
            const int c  = tid + i * 256;
            const int qc = c >> 8, rc = (c >> 1) & 127, hc = c & 1;
            int grow = bn * 128 + rc; if (grow > C_CLS - 1) grow = C_CLS - 1;
            const float* g = w + (size_t)grow * D_FEAT + k0 + qc * 8 + hc * 4;
            async_copy16(g, &Bs[(size_t)c * 4]);
        }
        __syncthreads();

        bf16x8 af[4];
        #pragma unroll
        for (int mi = 0; mi < 4; ++mi) {
            const int r = wm * 64 + mi * 16 + l15;
            af[mi] = *(const bf16x8*)&As[(size_t)(quad * 128 + r) * 8];
        }
        bf16x8 bfr[4];
        #pragma unroll
        for (int ni = 0; ni < 4; ++ni) {
            const int r = wn * 64 + ni * 16 + l15;
            const float* bp = &Bs[(size_t)(quad * 128 + r) * 8];
            f32x4 b0 = *(const f32x4*)bp;
            f32x4 b1 = *(const f32x4*)(bp + 4);
            bf16x8 t;
            t[0] = (__bf16)b0[0]; t[1] = (__bf16)b0[1]; t[2] = (__bf16)b0[2]; t[3] = (__bf16)b0[3];
            t[4] = (__bf16)b1[0]; t[5] = (__bf16)b1[1]; t[6] = (__bf16)b1[2]; t[7] = (__bf16)b1[3];
            bfr[ni] = t;
        }
        #pragma unroll
        for (int mi = 0; mi < 4; ++mi)
            #pragma unroll
            for (int ni = 0; ni < 4; ++ni)
                acc[mi][ni] = __builtin_amdgcn_mfma_f32_16x16x32_bf16(af[mi], bfr[ni], acc[mi][ni], 0, 0, 0);
        __syncthreads();
    }

    // ---- epilogue: cos -> margin -> exp(logit-64) -> per-row partial sums ----
    #pragma unroll
    for (int mi = 0; mi < 4; ++mi) {
        float rs[4] = {0.f, 0.f, 0.f, 0.f};
        #pragma unroll
        for (int ni = 0; ni < 4; ++ni) {
            const int lcol = wn * 64 + ni * 16 + l15;
            const int gcol = bn * 128 + lcol;
            const bool colv = (gcol < C_CLS);
            const float invw = inv_wn[colv ? gcol : (C_CLS - 1)];
            #pragma unroll
            for (int reg = 0; reg < 4; ++reg) {
                const int lrow = wm * 64 + mi * 16 + quad * 4 + reg;
                const float cosv = acc[mi][ni][reg] * invw;
                const float sinv = sqrtf(fmaxf(1.0f - cosv * cosv, 0.0f));
                const float phi  = (cosv > TH_) ? (cosv * COSM - sinv * SINM) : (cosv - MM_);
                const bool ist   = colv && (gcol == ys[lrow]);
                const float logit = 64.0f * (ist ? phi : cosv);
                if (ist) tlogit[bm * 128 + lrow] = logit;
                rs[reg] += colv ? __expf(logit - 64.0f) : 0.0f;
            }
        }
        #pragma unroll
        for (int reg = 0; reg < 4; ++reg) {
            float v = rs[reg];
            v += __shfl_xor(v, 8, 64);
            v += __shfl_xor(v, 4, 64);
            v += __shfl_xor(v, 2, 64);
            v += __shfl_xor(v, 1, 64);
            if (l15 == 0) {
                const int lrow = wm * 64 + mi * 16 + quad * 4 + reg;
                atomicAdd(&row_sum[bm * 128 + lrow], v);
            }
        }
    }
}

// ---------------- kernel 4: finalize loss ---------------------------------
__global__ void k_final(const float* __restrict__ row_sum, const float* __restrict__ tlogit,
                        float* __restrict__ out) {
    const int t = threadIdx.x;     // 512 threads
    float v = logf(row_sum[t]) + 64.0f - tlogit[t];
    #pragma unroll
    for (int m = 32; m >= 1; m >>= 1) v += __shfl_xor(v, m, 64);
    __shared__ float partial[8];
    if ((t & 63) == 0) partial[t >> 6] = v;
    __syncthreads();
    if (t == 0) {
        float s = 0.f;
        #pragma unroll
        for (int i = 0; i < 8; ++i) s += partial[i];
        out[0] = s * (1.0f / 512.0f);
    }
}

extern "C" void kernel_launch(void* const* d_in, const int* in_sizes, int n_in,
                              void* d_out, int out_size, void* d_ws, size_t ws_size,
                              hipStream_t stream) {
    const float* x = (const float*)d_in[0];
    const int*   y = (const int*)d_in[1];
    const float* w = (const float*)d_in[2];

    char* ws = (char*)d_ws;
    __bf16* xn      = (__bf16*)ws;                                  // 524288 B
    float*  inv_wn  = (float*)(ws + 524288);                        // 400000 B
    float*  row_sum = (float*)(ws + 524288 + 400000);               // 2048 B
    float*  tlogit  = (float*)(ws + 524288 + 400000 + 2048);        // 2048 B
    float*  out     = (float*)d_out;

    hipLaunchKernelGGL(k_xnorm, dim3(512), dim3(64), 0, stream, x, xn, row_sum, tlogit);
    hipLaunchKernelGGL(k_wnorm, dim3(25000), dim3(256), 0, stream, w, inv_wn);
    hipLaunchKernelGGL(k_gemm, dim3(4 * 782), dim3(256), 0, stream, xn, w, inv_wn, y, row_sum, tlogit);
    hipLaunchKernelGGL(k_final, dim3(1), dim3(512), 0, stream, row_sum, tlogit, out);
}